// Round 11
// baseline (270.386 us; speedup 1.0000x reference)
//
#include <hip/hip_runtime.h>
#include <cstdint>
#include <cstddef>

#define NB   16
#define NC   256
#define NPIX 3136
#define NW   56
#define EPSV 1e-5f

#define BSTR     (384 * NPIX)   // per-b Y stride (dwords)
#define OFF_VP   (128 * NPIX)   // per-b padded-v offset inside Y (dwords)
#define VROWD    36             // dwords per padded v row (72 bf16: 8 pad | 56 | 8 pad)
#define VPLANE   (56 * VROWD)   // 2016 dwords per padded v plane
#define OFF_PARTB 917504        // per-b Lc partials (64 slots x 1024 fp32), after padded v

// ws layout in dwords/floats
#define OFF_AB   0u        // Abf: 12 dtiles x 16 kchunks x 64 lanes x 4 dw = 49152
#define OFF_BNA  49152u    // [384]
#define OFF_BNB  49536u    // [384]
#define OFF_WT   49920u    // wtab: 32 chunks x 64 lanes x 4 dw = 8192
#define OFF_KS   58112u    // S[b][u][k] = 1024 (exp row sums)
#define OFF_Y    75520u    // Y[16][BSTR]; per-b: [0,32N) q bf16 uint2 planes;
                           // [64N,128N) k fp32; [128N,..) padded bf16 v; partials at OFF_PARTB

typedef short bf16x8 __attribute__((ext_vector_type(8)));
typedef float f32x4  __attribute__((ext_vector_type(4)));
typedef float f32x16 __attribute__((ext_vector_type(16)));

__device__ __forceinline__ uint32_t f2bf(float f) {
  uint32_t x = __float_as_uint(f);
  uint32_t r = x + 0x7fffu + ((x >> 16) & 1u);
  return r >> 16;
}
// HW packed f32->bf16 pair (RNE), 1 VALU vs ~5 for the manual pair
__device__ __forceinline__ uint32_t cvtpk(float lo, float hi) {
  uint32_t r;
  asm("v_cvt_pk_bf16_f32 %0, %1, %2" : "=v"(r) : "v"(lo), "v"(hi));
  return r;
}

__device__ __forceinline__ float fetchW(const float* Wq, const float* Wk,
                                        const float* Wv, int m, int c) {
  if (m < 64)  return Wq[c * 64 + m];
  if (m < 128) return Wk[c * 64 + (m - 64)];
  return Wv[c * 256 + (m - 128)];
}

// ---------------- prep: bf16 A-fragments, BN coeffs, pos-w fragments, zero S --
__global__ void prep_kernel(const float* __restrict__ Wq, const float* __restrict__ Wk,
                            const float* __restrict__ Wv, const float* __restrict__ pos_w,
                            const float* __restrict__ gq, const float* __restrict__ bq,
                            const float* __restrict__ mq, const float* __restrict__ vq,
                            const float* __restrict__ gv, const float* __restrict__ bv,
                            const float* __restrict__ mv, const float* __restrict__ vv,
                            float* __restrict__ ws) {
  int d = blockIdx.x;    // 0..383
  int c = threadIdx.x;   // 0..255
  int i = d * 256 + c;
  if (i < 49152) {
    int dgt = i >> 12, rem = i & 4095;
    int kc = rem >> 8, rem2 = rem & 255;
    int lane = rem2 >> 2, dp = rem2 & 3;
    int m = dgt * 32 + (lane & 31);
    int k0 = kc * 16 + (lane >> 5) * 8 + dp * 2;
    float w0 = fetchW(Wq, Wk, Wv, m, k0);
    float w1 = fetchW(Wq, Wk, Wv, m, k0 + 1);
    ((uint32_t*)(ws + OFF_AB))[i] = f2bf(w0) | (f2bf(w1) << 16);
  }
  if (c == 0) {
    float sa, sb;
    if (d < 64)        { float inv = gq[d] / sqrtf(vq[d] + EPSV); sa = inv; sb = bq[d] - mq[d] * inv; }
    else if (d < 128)  { sa = 1.0f; sb = 0.0f; }
    else               { int j = d - 128; float inv = gv[j] / sqrtf(vv[j] + EPSV); sa = inv; sb = bv[j] - mv[j] * inv; }
    ws[OFF_BNA + d] = sa;
    ws[OFF_BNB + d] = sb;
  }
  if (i < 8192) {
    int chunk = i >> 8, rem = i & 255, lane = rem >> 2, dp = rem & 3;
    int quad = lane >> 4, k = lane & 15;
    int u = chunk >> 3, t = chunk & 7;
    int dh = 2 * t + (quad >> 1);
    int dwb = (quad & 1) * 8 + dp * 2;
    float w0 = (dh < 15 && dwb     < 15) ? pos_w[k * 900 + u * 225 + dh * 15 + dwb]     : 0.0f;
    float w1 = (dh < 15 && dwb + 1 < 15) ? pos_w[k * 900 + u * 225 + dh * 15 + dwb + 1] : 0.0f;
    ((uint32_t*)(ws + OFF_WT))[i] = f2bf(w0) | (f2bf(w1) << 16);
  }
  if (i < 1024) ws[OFF_KS + i] = 0.0f;
  // zero left/right pads of padded-v rows: 4096 planes x 56 rows, dw {0..3},{32..35}
  for (int g = i; g < 4096 * 56; g += 98304) {
    int plane = g / 56, r = g - plane * 56;
    int bb = plane >> 8, d2 = plane & 255;
    uint32_t* row = (uint32_t*)(ws + OFF_Y) + (size_t)bb * BSTR + OFF_VP
                    + (size_t)d2 * VPLANE + r * VROWD;
    uint4 z; z.x = 0; z.y = 0; z.z = 0; z.w = 0;
    *(uint4*)(row)      = z;
    *(uint4*)(row + 32) = z;
  }
}

// ---------------- stage 1: QKV projection via MFMA 32x32x16 bf16 --------------
// Waves 1-3 (and wave 0's dt=2 tile) swap MFMA operands (A/B lane maps are
// identical for 32x32x16) so acc holds pixel-rows x d-cols: vectorized k
// (float4) and v (uint2) stores. All bf16 packing via v_cvt_pk_bf16_f32.
__launch_bounds__(256, 2)
__global__ void qkv_mfma(const float* __restrict__ x, const float* __restrict__ wsc,
                         float* __restrict__ Y) {
  __shared__ uint32_t X[64 * 128];   // 32 KB
  __shared__ float BNs[768];
  int tid = threadIdx.x;
  int n0 = blockIdx.x * 64, b = blockIdx.y;
  for (int i = tid; i < 768; i += 256) BNs[i] = wsc[OFF_BNA + i];
  const size_t xb = (size_t)b * NC * NPIX;
#pragma unroll
  for (int it = 0; it < 4; ++it) {
    int n2 = tid & 31;
    int cp4 = it * 8 + (tid >> 5);
    const float* xp = x + xb + (size_t)(cp4 * 8) * NPIX + n0 + n2 * 2;
    float2 ld[8];
#pragma unroll
    for (int j = 0; j < 8; ++j) ld[j] = *(const float2*)(xp + (size_t)j * NPIX);
    uint4 ve, vo;
    ve.x = cvtpk(ld[0].x, ld[1].x);
    ve.y = cvtpk(ld[2].x, ld[3].x);
    ve.z = cvtpk(ld[4].x, ld[5].x);
    ve.w = cvtpk(ld[6].x, ld[7].x);
    vo.x = cvtpk(ld[0].y, ld[1].y);
    vo.y = cvtpk(ld[2].y, ld[3].y);
    vo.z = cvtpk(ld[4].y, ld[5].y);
    vo.w = cvtpk(ld[6].y, ld[7].y);
    int ne = 2 * n2, no = ne + 1;
    *(uint4*)(X + ne * 128 + ((cp4 ^ (ne & 31)) << 2)) = ve;
    *(uint4*)(X + no * 128 + ((cp4 ^ (no & 31)) << 2)) = vo;
  }
  __syncthreads();
  int lane = tid & 63, w = tid >> 6;
  int n31 = lane & 31, h5 = lane >> 5;
  f32x16 acc[3][2];
#pragma unroll
  for (int dt = 0; dt < 3; ++dt)
#pragma unroll
    for (int nt = 0; nt < 2; ++nt)
#pragma unroll
      for (int e = 0; e < 16; ++e) acc[dt][nt][e] = 0.0f;
  const uint4* AB = (const uint4*)(wsc + OFF_AB);
  if (w == 0) {
#pragma unroll 4
    for (int kc = 0; kc < 16; ++kc) {
      bf16x8 af[3];
#pragma unroll
      for (int dt = 0; dt < 3; ++dt) {
        union { uint4 q; bf16x8 v; } tmp;
        tmp.q = AB[(size_t)((dt * 16 + kc)) * 64 + lane];
        af[dt] = tmp.v;
      }
#pragma unroll
      for (int nt = 0; nt < 2; ++nt) {
        union { uint4 q; bf16x8 v; } bu;
        bu.q = *(const uint4*)(X + (nt * 32 + n31) * 128 + (((2 * kc + h5) ^ n31) << 2));
        acc[0][nt] = __builtin_amdgcn_mfma_f32_32x32x16_bf16(af[0], bu.v, acc[0][nt], 0, 0, 0);
        acc[1][nt] = __builtin_amdgcn_mfma_f32_32x32x16_bf16(af[1], bu.v, acc[1][nt], 0, 0, 0);
        acc[2][nt] = __builtin_amdgcn_mfma_f32_32x32x16_bf16(bu.v, af[2], acc[2][nt], 0, 0, 0);
      }
    }
  } else {
#pragma unroll 4
    for (int kc = 0; kc < 16; ++kc) {
      bf16x8 af[3];
#pragma unroll
      for (int dt = 0; dt < 3; ++dt) {
        union { uint4 q; bf16x8 v; } tmp;
        tmp.q = AB[(size_t)(((w * 3 + dt) * 16 + kc)) * 64 + lane];
        af[dt] = tmp.v;
      }
#pragma unroll
      for (int nt = 0; nt < 2; ++nt) {
        union { uint4 q; bf16x8 v; } bu;
        bu.q = *(const uint4*)(X + (nt * 32 + n31) * 128 + (((2 * kc + h5) ^ n31) << 2));
#pragma unroll
        for (int dt = 0; dt < 3; ++dt)
          acc[dt][nt] = __builtin_amdgcn_mfma_f32_32x32x16_bf16(bu.v, af[dt], acc[dt][nt], 0, 0, 0);
      }
    }
  }
  // pixel-run indices for swapped-orientation stores
  int prr[2][4], pcc[2][4];
#pragma unroll
  for (int nt = 0; nt < 2; ++nt)
#pragma unroll
    for (int j = 0; j < 4; ++j) {
      int pb = n0 + nt * 32 + 8 * j + 4 * h5;
      prr[nt][j] = pb / NW;
      pcc[nt][j] = pb - prr[nt][j] * NW;
    }
  if (w == 0) {
    // dt 0,1: old orientation (col = pixel, rows = d) -> q bf16 pairs
#pragma unroll
    for (int dt = 0; dt < 2; ++dt) {
      int dgt = dt;
      float sa[16], sb[16];
#pragma unroll
      for (int g = 0; g < 4; ++g) {
        *(float4*)(sa + g * 4) = *(const float4*)(BNs + dgt * 32 + g * 8 + h5 * 4);
        *(float4*)(sb + g * 4) = *(const float4*)(BNs + 384 + dgt * 32 + g * 8 + h5 * 4);
      }
#pragma unroll
      for (int nt = 0; nt < 2; ++nt) {
        int pix = n0 + nt * 32 + n31;
        uint2* qb2 = (uint2*)(Y + (size_t)b * BSTR);
#pragma unroll
        for (int g = 0; g < 4; ++g) {
          float y0 = fmaf(acc[dt][nt][4 * g + 0], sa[4 * g + 0], sb[4 * g + 0]);
          float y1 = fmaf(acc[dt][nt][4 * g + 1], sa[4 * g + 1], sb[4 * g + 1]);
          float y2 = fmaf(acc[dt][nt][4 * g + 2], sa[4 * g + 2], sb[4 * g + 2]);
          float y3 = fmaf(acc[dt][nt][4 * g + 3], sa[4 * g + 3], sb[4 * g + 3]);
          uint2 val;
          val.x = cvtpk(y0, y1);
          val.y = cvtpk(y2, y3);
          qb2[(size_t)(dgt * 8 + 2 * g + h5) * NPIX + pix] = val;
        }
      }
    }
    // dt 2 swapped: k planes 64..95, fp32 vectorized (identity BN)
    {
      float* kp = Y + ((size_t)(b * 384) + 64 + n31) * NPIX;
#pragma unroll
      for (int nt = 0; nt < 2; ++nt)
#pragma unroll
        for (int j = 0; j < 4; ++j) {
          float4 st;
          st.x = acc[2][nt][4 * j + 0];
          st.y = acc[2][nt][4 * j + 1];
          st.z = acc[2][nt][4 * j + 2];
          st.w = acc[2][nt][4 * j + 3];
          *(float4*)(kp + prr[nt][j] * NW + pcc[nt][j]) = st;
        }
    }
  } else {
    // swapped orientation: rows = pixels (runs of 4), col = d = dgt*32 + n31
    unsigned short* vp = (unsigned short*)(Y + (size_t)b * BSTR + OFF_VP);
#pragma unroll
    for (int dt = 0; dt < 3; ++dt) {
      int dgt = w * 3 + dt;
      if (dgt == 3) {              // k planes 96..127, fp32, identity BN
        float* kp = Y + ((size_t)(b * 384) + 96 + n31) * NPIX;
#pragma unroll
        for (int nt = 0; nt < 2; ++nt)
#pragma unroll
          for (int j = 0; j < 4; ++j) {
            float4 st;
            st.x = acc[dt][nt][4 * j + 0];
            st.y = acc[dt][nt][4 * j + 1];
            st.z = acc[dt][nt][4 * j + 2];
            st.w = acc[dt][nt][4 * j + 3];
            *(float4*)(kp + prr[nt][j] * NW + pcc[nt][j]) = st;
          }
      } else {                     // v planes, bf16 packed pairs into padded layout
        int d2 = dgt * 32 + n31 - 128;
        float sa = BNs[dgt * 32 + n31];
        float sb2 = BNs[384 + dgt * 32 + n31];
        unsigned short* vpd = vp + (size_t)d2 * 4032;
#pragma unroll
        for (int nt = 0; nt < 2; ++nt)
#pragma unroll
          for (int j = 0; j < 4; ++j) {
            float y0 = fmaf(acc[dt][nt][4 * j + 0], sa, sb2);
            float y1 = fmaf(acc[dt][nt][4 * j + 1], sa, sb2);
            float y2 = fmaf(acc[dt][nt][4 * j + 2], sa, sb2);
            float y3 = fmaf(acc[dt][nt][4 * j + 3], sa, sb2);
            uint2 val;
            val.x = cvtpk(y0, y1);
            val.y = cvtpk(y2, y3);
            *(uint2*)(vpd + prr[nt][j] * 72 + 8 + pcc[nt][j]) = val;
          }
      }
    }
  }
}

// ---------------- stage 2: Lc partials via MFMA, exp(k) inline ----------------
__launch_bounds__(256)
__global__ void lc_mfma(float* __restrict__ Y, float* __restrict__ ws) {
  __shared__ float R[4096];
  __shared__ float Rs[64];
  int bx = blockIdx.x, u = blockIdx.y, b = blockIdx.z;
  int tid = threadIdx.x;
  int lane = tid & 63, w = tid >> 6;
  int col = lane & 15, quad = lane >> 4;
  int slot = bx * 4 + w;
  const float* krow = Y + ((size_t)(b * 384 + 64 + u * 16 + col)) * NPIX;
  const uint32_t* vpb = (const uint32_t*)(Y + (size_t)b * BSTR + OFF_VP)
                        + (size_t)(u * 64 + col) * VPLANE;
  f32x4 acc[4];
#pragma unroll
  for (int vt = 0; vt < 4; ++vt) acc[vt] = (f32x4){0.f, 0.f, 0.f, 0.f};
  float ssum = 0.0f;
  for (int c = slot; c < 126; c += 64) {
    int p0 = c * 32 + quad * 8;
    int row = p0 / 72;
    int pc = p0 - row * 72;
    bool valid = (unsigned)(pc - 8) < 56u;   // pc in {8..56} -> real cols
    float4 k0, k1;
    if (valid) {
      const float* kp = krow + row * NW + pc - 8;
      k0 = *(const float4*)(kp);
      k1 = *(const float4*)(kp + 4);
    } else {
      k0.x = k0.y = k0.z = k0.w = -1e30f;
      k1 = k0;
    }
    float e0 = __expf(k0.x), e1 = __expf(k0.y), e2 = __expf(k0.z), e3 = __expf(k0.w);
    float e4 = __expf(k1.x), e5 = __expf(k1.y), e6 = __expf(k1.z), e7 = __expf(k1.w);
    ssum += (e0 + e1 + e2 + e3) + (e4 + e5 + e6 + e7);
    union { uint32_t d[4]; bf16x8 v; } kb;
    kb.d[0] = cvtpk(e0, e1);
    kb.d[1] = cvtpk(e2, e3);
    kb.d[2] = cvtpk(e4, e5);
    kb.d[3] = cvtpk(e6, e7);
    int vdw = c * 16 + quad * 4;
#pragma unroll
    for (int vt = 0; vt < 4; ++vt) {
      union { uint4 q; bf16x8 v; } vb;
      vb.q = *(const uint4*)(vpb + (size_t)(vt * 16) * VPLANE + vdw);
      acc[vt] = __builtin_amdgcn_mfma_f32_16x16x32_bf16(vb.v, kb.v, acc[vt], 0, 0, 0);
    }
  }
  ssum += __shfl_xor(ssum, 16);
  ssum += __shfl_xor(ssum, 32);
#pragma unroll
  for (int vt = 0; vt < 4; ++vt)
#pragma unroll
    for (int r = 0; r < 4; ++r)
      R[w * 1024 + vt * 256 + quad * 64 + r * 16 + col] = acc[vt][r];
  if (lane < 16) Rs[w * 16 + col] = ssum;
  __syncthreads();
  float* P = Y + (size_t)b * BSTR + OFF_PARTB + (size_t)(u * 16 + bx) * 1024;
  float4 s0 = *(const float4*)(R + tid * 4);
  float4 s1 = *(const float4*)(R + 1024 + tid * 4);
  float4 s2 = *(const float4*)(R + 2048 + tid * 4);
  float4 s3 = *(const float4*)(R + 3072 + tid * 4);
  float4 tot;
  tot.x = (s0.x + s1.x) + (s2.x + s3.x);
  tot.y = (s0.y + s1.y) + (s2.y + s3.y);
  tot.z = (s0.z + s1.z) + (s2.z + s3.z);
  tot.w = (s0.w + s1.w) + (s2.w + s3.w);
  *(float4*)(P + tid * 4) = tot;
  if (tid < 16)
    atomicAdd(&ws[OFF_KS + b * 64 + u * 16 + tid],
              (Rs[tid] + Rs[16 + tid]) + (Rs[32 + tid] + Rs[48 + tid]));
}

// ---------------- stage 3: MFMA position conv + fused Lc-reduce + output ------
#define ROWS    29
#define RSTR2   72
#define UPITCH2 2088   // ROWS * RSTR2
#define LDSW2   8352   // 4 * UPITCH2

// Fully-unrolled conv core with compile-time phase window (halo skip).
template<int PPLO, int PPHI>
__device__ __forceinline__ void conv_accum(const uint32_t* __restrict__ S,
                                           const uint4* __restrict__ wt,
                                           int abase, int lane, f32x4* acc) {
#pragma unroll 1
  for (int u = 0; u < 4; ++u) {
    bf16x8 wf[8];
#pragma unroll
    for (int t = 0; t < 8; ++t) {
      union { uint4 q; bf16x8 v; } tmp;
      tmp.q = wt[(u * 8 + t) * 64 + lane];
      wf[t] = tmp.v;
    }
    int au = u * UPITCH2 + abase;
#pragma unroll
    for (int PP = PPLO; PP < PPHI; ++PP) {
      int a = au + PP * (2 * RSTR2);
      union { uint32_t u4[4]; bf16x8 v8; } bu;
      bu.u4[0] = S[a];     bu.u4[1] = S[a + 2];
      bu.u4[2] = S[a + 4]; bu.u4[3] = S[a + 6];
#pragma unroll
      for (int t = 0; t < 8; ++t) {
        int q = PP - t;
        if (q >= 0 && q < 7)
          acc[q] = __builtin_amdgcn_mfma_f32_16x16x32_bf16(wf[t], bu.v8, acc[q], 0, 0, 0);
      }
    }
  }
}

__launch_bounds__(512, 4)
__global__ void pos_lambda_mfma(const float* __restrict__ Y, const float* __restrict__ wsc,
                                const float* __restrict__ pos_b, float* __restrict__ out) {
  __shared__ __attribute__((aligned(16))) uint32_t S[LDSW2];
  __shared__ float Lpart[64];
  int v = blockIdx.x, b = blockIdx.y, band = blockIdx.z;
  int rb = band * 14;
  int tid = threadIdx.x;
  // ---- stage padded v rows from pre-padded bf16 planes ----
  const uint32_t* vpad = (const uint32_t*)(Y + (size_t)b * BSTR + OFF_VP);
  for (int ii = tid; ii < 1044; ii += 512) {
    int u = ii / 261;
    int rem = ii - u * 261;
    int row = rem / 9;
    int j3 = rem - row * 9;
    int gr = rb + row - 7;
    uint32_t d0 = 0, d1 = 0, d2 = 0, d3 = 0, d4 = 0;
    if ((unsigned)gr < (unsigned)NW) {
      const uint32_t* pr32 = vpad + (size_t)(u * 64 + v) * VPLANE + gr * VROWD + 4 * j3;
      uint4 q4 = *(const uint4*)pr32;
      d0 = q4.x; d1 = q4.y; d2 = q4.z; d3 = q4.w;
      d4 = pr32[4];
    }
    uint32_t* dst = S + u * UPITCH2 + row * RSTR2 + 8 * j3;
    uint4 w0, w1;
    w0.x = __builtin_amdgcn_alignbit(d1, d0, 16);  w0.y = d1;
    w0.z = __builtin_amdgcn_alignbit(d2, d1, 16);  w0.w = d2;
    w1.x = __builtin_amdgcn_alignbit(d3, d2, 16);  w1.y = d3;
    w1.z = __builtin_amdgcn_alignbit(d4, d3, 16);  w1.w = d4;
    *(uint4*)(dst)     = w0;
    *(uint4*)(dst + 4) = w1;
  }
  // ---- fused lc_reduce: threads 0..255 compute Lc[u][k] terms for this (b,v).
  // t = (u*16+k)*4 + s4; each sums 4 s-slots, 2-step shfl reduce over s4,
  // scale by 1/S. Hidden under the staging loads; uses the same barrier.
  if (tid < 256) {
    int u_ = tid >> 6, kk = (tid >> 2) & 15, s4 = tid & 3;
    const float* P = Y + (size_t)b * BSTR + OFF_PARTB;
    int base = v * 16 + kk;
    float val = 0.0f;
#pragma unroll
    for (int j = 0; j < 4; ++j)
      val += P[(size_t)(u_ * 16 + s4 * 4 + j) * 1024 + base];
    val += __shfl_xor(val, 1);
    val += __shfl_xor(val, 2);
    if (s4 == 0)
      Lpart[u_ * 16 + kk] = val / wsc[OFF_KS + b * 64 + u_ * 16 + kk];
  }
  __syncthreads();
  int lane = tid & 63, wid = tid >> 6;
  int quad = lane >> 4, n = lane & 15;
  int dhp = quad >> 1;
  int ct = wid & 3, p = wid >> 2;
  int cb = (ct == 3) ? 40 : ct * 16;
  int sb = cb + n + (quad & 1) * 8;
  int abase = (p + dhp) * RSTR2 + sb;
  const uint4* wt = (const uint4*)(wsc + OFF_WT);
  // Lc + pos_b folded into the MFMA C-initializer
  float lcq[4];
#pragma unroll
  for (int r = 0; r < 4; ++r) {
    int k = quad * 4 + r;
    lcq[r] = ((Lpart[k] + Lpart[16 + k]) + (Lpart[32 + k] + Lpart[48 + k])) + pos_b[k];
  }
  f32x4 acc[7];
#pragma unroll
  for (int q = 0; q < 7; ++q) {
    acc[q][0] = lcq[0]; acc[q][1] = lcq[1]; acc[q][2] = lcq[2]; acc[q][3] = lcq[3];
  }
  // halo skip: band0 stages zero rows 0..6 -> phases 0..2 all-zero; band3 stages
  // zero rows 21..28 -> phases 11..13 all-zero. Compile-time windows.
  if (band == 0)      conv_accum<3, 14>(S, wt, abase, lane, acc);
  else if (band == 3) conv_accum<0, 11>(S, wt, abase, lane, acc);
  else                conv_accum<0, 14>(S, wt, abase, lane, acc);

  const uint2* qb2 = (const uint2*)(Y + (size_t)b * BSTR);
#pragma unroll
  for (int q = 0; q < 7; ++q) {
    int rr = rb + p + 2 * q;
    int pix = rr * NW + cb + n;
    float m0 = acc[q][0], m1 = acc[q][1];
    float m2 = acc[q][2], m3 = acc[q][3];
    float pp[4];
#pragma unroll
    for (int j = 0; j < 4; ++j) {
      int h = quad ^ j;
      uint2 qd = qb2[(h * 4 + quad) * NPIX + pix];
      float q0 = __uint_as_float(qd.x << 16);
      float q1 = __uint_as_float(qd.x & 0xffff0000u);
      float q2 = __uint_as_float(qd.y << 16);
      float q3 = __uint_as_float(qd.y & 0xffff0000u);
      pp[j] = fmaf(q0, m0, fmaf(q1, m1, fmaf(q2, m2, q3 * m3)));
    }
    float t0 = pp[0] + __shfl_xor(pp[1], 16);
    float t2 = pp[2] + __shfl_xor(pp[3], 16);
    float y  = t0 + __shfl_xor(t2, 32);
    out[((size_t)(b * 256 + quad * 64 + v)) * NPIX + pix] = y;
  }
}

extern "C" void kernel_launch(void* const* d_in, const int* in_sizes, int n_in,
                              void* d_out, int out_size, void* d_ws, size_t ws_size,
                              hipStream_t stream) {
  const float* x     = (const float*)d_in[0];
  const float* Wq    = (const float*)d_in[1];
  const float* Wk    = (const float*)d_in[2];
  const float* Wv    = (const float*)d_in[3];
  const float* pos_w = (const float*)d_in[4];
  const float* pos_b = (const float*)d_in[5];
  const float* gq    = (const float*)d_in[6];
  const float* bq    = (const float*)d_in[7];
  const float* mq    = (const float*)d_in[8];
  const float* vq    = (const float*)d_in[9];
  const float* gv    = (const float*)d_in[10];
  const float* bv    = (const float*)d_in[11];
  const float* mv    = (const float*)d_in[12];
  const float* vv    = (const float*)d_in[13];
  float* ws  = (float*)d_ws;
  float* out = (float*)d_out;
  float* Y   = ws + OFF_Y;

  prep_kernel<<<dim3(384), 256, 0, stream>>>(Wq, Wk, Wv, pos_w, gq, bq, mq, vq,
                                             gv, bv, mv, vv, ws);
  qkv_mfma<<<dim3(49, 16), 256, 0, stream>>>(x, ws, Y);
  lc_mfma<<<dim3(16, 4, 16), 256, 0, stream>>>(Y, ws);
  pos_lambda_mfma<<<dim3(64, 16, 4), 512, 0, stream>>>(Y, ws, pos_b, out);
}

// Round 12
// 255.138 us; speedup vs baseline: 1.0598x; 1.0598x over previous
//
#include <hip/hip_runtime.h>
#include <cstdint>
#include <cstddef>

#define NB   16
#define NC   256
#define NPIX 3136
#define NW   56
#define EPSV 1e-5f

#define BSTR     (384 * NPIX)   // per-b Y stride (dwords)
#define OFF_VP   (128 * NPIX)   // per-b padded-v offset inside Y (dwords)
#define VROWD    36             // dwords per padded v row (72 bf16: 8 pad | 56 | 8 pad)
#define VPLANE   (56 * VROWD)   // 2016 dwords per padded v plane
#define OFF_PARTB 917504        // per-b Lc partials (64 slots x 1024 fp32), after padded v

// ws layout in dwords/floats
#define OFF_AB   0u        // Abf: 12 dtiles x 16 kchunks x 64 lanes x 4 dw = 49152
#define OFF_BNA  49152u    // [384]
#define OFF_BNB  49536u    // [384]
#define OFF_WT   49920u    // wtab: 32 chunks x 64 lanes x 4 dw = 8192
#define OFF_KS   58112u    // S[b][u][k] = 1024 (exp row sums)
#define OFF_LC   59136u    // Lc[16][16][64] = 16384
#define OFF_Y    75520u    // Y[16][BSTR]; per-b: [0,32N) q bf16 uint2 planes;
                           // [64N,128N) k fp32; [128N,..) padded bf16 v; partials at OFF_PARTB

typedef short bf16x8 __attribute__((ext_vector_type(8)));
typedef float f32x4  __attribute__((ext_vector_type(4)));
typedef float f32x16 __attribute__((ext_vector_type(16)));

__device__ __forceinline__ uint32_t f2bf(float f) {
  uint32_t x = __float_as_uint(f);
  uint32_t r = x + 0x7fffu + ((x >> 16) & 1u);
  return r >> 16;
}
// truncating bf16 pair pack: 3 VALU vs ~9 for round-nearest
__device__ __forceinline__ uint32_t pk_trunc(float a, float b) {
  return (__float_as_uint(a) >> 16) | (__float_as_uint(b) & 0xffff0000u);
}

__device__ __forceinline__ float fetchW(const float* Wq, const float* Wk,
                                        const float* Wv, int m, int c) {
  if (m < 64)  return Wq[c * 64 + m];
  if (m < 128) return Wk[c * 64 + (m - 64)];
  return Wv[c * 256 + (m - 128)];
}

// ---------------- prep: bf16 A-fragments, BN coeffs, pos-w fragments, zero S --
__global__ void prep_kernel(const float* __restrict__ Wq, const float* __restrict__ Wk,
                            const float* __restrict__ Wv, const float* __restrict__ pos_w,
                            const float* __restrict__ gq, const float* __restrict__ bq,
                            const float* __restrict__ mq, const float* __restrict__ vq,
                            const float* __restrict__ gv, const float* __restrict__ bv,
                            const float* __restrict__ mv, const float* __restrict__ vv,
                            float* __restrict__ ws) {
  int d = blockIdx.x;    // 0..383
  int c = threadIdx.x;   // 0..255
  int i = d * 256 + c;
  if (i < 49152) {
    int dgt = i >> 12, rem = i & 4095;
    int kc = rem >> 8, rem2 = rem & 255;
    int lane = rem2 >> 2, dp = rem2 & 3;
    int m = dgt * 32 + (lane & 31);
    int k0 = kc * 16 + (lane >> 5) * 8 + dp * 2;
    float w0 = fetchW(Wq, Wk, Wv, m, k0);
    float w1 = fetchW(Wq, Wk, Wv, m, k0 + 1);
    ((uint32_t*)(ws + OFF_AB))[i] = f2bf(w0) | (f2bf(w1) << 16);
  }
  if (c == 0) {
    float sa, sb;
    if (d < 64)        { float inv = gq[d] / sqrtf(vq[d] + EPSV); sa = inv; sb = bq[d] - mq[d] * inv; }
    else if (d < 128)  { sa = 1.0f; sb = 0.0f; }
    else               { int j = d - 128; float inv = gv[j] / sqrtf(vv[j] + EPSV); sa = inv; sb = bv[j] - mv[j] * inv; }
    ws[OFF_BNA + d] = sa;
    ws[OFF_BNB + d] = sb;
  }
  if (i < 8192) {
    int chunk = i >> 8, rem = i & 255, lane = rem >> 2, dp = rem & 3;
    int quad = lane >> 4, k = lane & 15;
    int u = chunk >> 3, t = chunk & 7;
    int dh = 2 * t + (quad >> 1);
    int dwb = (quad & 1) * 8 + dp * 2;
    float w0 = (dh < 15 && dwb     < 15) ? pos_w[k * 900 + u * 225 + dh * 15 + dwb]     : 0.0f;
    float w1 = (dh < 15 && dwb + 1 < 15) ? pos_w[k * 900 + u * 225 + dh * 15 + dwb + 1] : 0.0f;
    ((uint32_t*)(ws + OFF_WT))[i] = f2bf(w0) | (f2bf(w1) << 16);
  }
  if (i < 1024) ws[OFF_KS + i] = 0.0f;
  // zero left/right pads of padded-v rows: 4096 planes x 56 rows, dw {0..3},{32..35}
  for (int g = i; g < 4096 * 56; g += 98304) {
    int plane = g / 56, r = g - plane * 56;
    int bb = plane >> 8, d2 = plane & 255;
    uint32_t* row = (uint32_t*)(ws + OFF_Y) + (size_t)bb * BSTR + OFF_VP
                    + (size_t)d2 * VPLANE + r * VROWD;
    uint4 z; z.x = 0; z.y = 0; z.z = 0; z.w = 0;
    *(uint4*)(row)      = z;
    *(uint4*)(row + 32) = z;
  }
}

// ---------------- stage 1: QKV projection via MFMA 32x32x16 bf16 --------------
__launch_bounds__(256, 2)
__global__ void qkv_mfma(const float* __restrict__ x, const float* __restrict__ wsc,
                         float* __restrict__ Y) {
  __shared__ uint32_t X[64 * 128];   // 32 KB
  __shared__ float BNs[768];
  int tid = threadIdx.x;
  int n0 = blockIdx.x * 64, b = blockIdx.y;
  for (int i = tid; i < 768; i += 256) BNs[i] = wsc[OFF_BNA + i];
  const size_t xb = (size_t)b * NC * NPIX;
#pragma unroll
  for (int it = 0; it < 4; ++it) {
    int n2 = tid & 31;
    int cp4 = it * 8 + (tid >> 5);
    const float* xp = x + xb + (size_t)(cp4 * 8) * NPIX + n0 + n2 * 2;
    float2 ld[8];
#pragma unroll
    for (int j = 0; j < 8; ++j) ld[j] = *(const float2*)(xp + (size_t)j * NPIX);
    uint32_t e0, e1, e2, e3, o0, o1, o2, o3;
    e0 = f2bf(ld[0].x) | (f2bf(ld[1].x) << 16);
    e1 = f2bf(ld[2].x) | (f2bf(ld[3].x) << 16);
    e2 = f2bf(ld[4].x) | (f2bf(ld[5].x) << 16);
    e3 = f2bf(ld[6].x) | (f2bf(ld[7].x) << 16);
    o0 = f2bf(ld[0].y) | (f2bf(ld[1].y) << 16);
    o1 = f2bf(ld[2].y) | (f2bf(ld[3].y) << 16);
    o2 = f2bf(ld[4].y) | (f2bf(ld[5].y) << 16);
    o3 = f2bf(ld[6].y) | (f2bf(ld[7].y) << 16);
    int ne = 2 * n2, no = ne + 1;
    uint4 ve; ve.x = e0; ve.y = e1; ve.z = e2; ve.w = e3;
    uint4 vo; vo.x = o0; vo.y = o1; vo.z = o2; vo.w = o3;
    *(uint4*)(X + ne * 128 + ((cp4 ^ (ne & 31)) << 2)) = ve;
    *(uint4*)(X + no * 128 + ((cp4 ^ (no & 31)) << 2)) = vo;
  }
  __syncthreads();
  int lane = tid & 63, w = tid >> 6;
  int n31 = lane & 31, h5 = lane >> 5;
  f32x16 acc[3][2];
#pragma unroll
  for (int dt = 0; dt < 3; ++dt)
#pragma unroll
    for (int nt = 0; nt < 2; ++nt)
#pragma unroll
      for (int e = 0; e < 16; ++e) acc[dt][nt][e] = 0.0f;
  const uint4* AB = (const uint4*)(wsc + OFF_AB);
#pragma unroll 4
  for (int kc = 0; kc < 16; ++kc) {
    bf16x8 af[3];
#pragma unroll
    for (int dt = 0; dt < 3; ++dt) {
      union { uint4 q; bf16x8 v; } tmp;
      tmp.q = AB[(size_t)(((w * 3 + dt) * 16 + kc)) * 64 + lane];
      af[dt] = tmp.v;
    }
#pragma unroll
    for (int nt = 0; nt < 2; ++nt) {
      union { uint4 q; bf16x8 v; } bu;
      bu.q = *(const uint4*)(X + (nt * 32 + n31) * 128 + (((2 * kc + h5) ^ n31) << 2));
#pragma unroll
      for (int dt = 0; dt < 3; ++dt)
        acc[dt][nt] = __builtin_amdgcn_mfma_f32_32x32x16_bf16(af[dt], bu.v, acc[dt][nt], 0, 0, 0);
    }
  }
#pragma unroll
  for (int dt = 0; dt < 3; ++dt) {
    int dgt = w * 3 + dt;
    float sa[16], sb[16];
#pragma unroll
    for (int g = 0; g < 4; ++g) {
      *(float4*)(sa + g * 4) = *(const float4*)(BNs + dgt * 32 + g * 8 + h5 * 4);
      *(float4*)(sb + g * 4) = *(const float4*)(BNs + 384 + dgt * 32 + g * 8 + h5 * 4);
    }
#pragma unroll
    for (int nt = 0; nt < 2; ++nt) {
      int pix = n0 + nt * 32 + n31;
      if (dgt < 2) {             // q planes: bf16 pairs [16 grp][pix] uint2
        uint2* qb2 = (uint2*)(Y + (size_t)b * BSTR);
#pragma unroll
        for (int g = 0; g < 4; ++g) {
          float y0 = fmaf(acc[dt][nt][4 * g + 0], sa[4 * g + 0], sb[4 * g + 0]);
          float y1 = fmaf(acc[dt][nt][4 * g + 1], sa[4 * g + 1], sb[4 * g + 1]);
          float y2 = fmaf(acc[dt][nt][4 * g + 2], sa[4 * g + 2], sb[4 * g + 2]);
          float y3 = fmaf(acc[dt][nt][4 * g + 3], sa[4 * g + 3], sb[4 * g + 3]);
          uint2 val;
          val.x = f2bf(y0) | (f2bf(y1) << 16);
          val.y = f2bf(y2) | (f2bf(y3) << 16);
          qb2[(size_t)(dgt * 8 + 2 * g + h5) * NPIX + pix] = val;
        }
      } else if (dgt < 4) {      // k planes 64..127, fp32 linear
#pragma unroll
        for (int g = 0; g < 4; ++g)
#pragma unroll
          for (int ki = 0; ki < 4; ++ki) {
            int d = dgt * 32 + 8 * g + 4 * h5 + ki;
            Y[((size_t)b * 384 + d) * NPIX + pix] =
                fmaf(acc[dt][nt][4 * g + ki], sa[4 * g + ki], sb[4 * g + ki]);
          }
      } else {                   // v planes, bf16 round-nearest into padded layout
        int pr = pix / NW, pc = pix - pr * NW;
        int ridx = pr * 72 + 8 + pc;
        unsigned short* vp = (unsigned short*)(Y + (size_t)b * BSTR + OFF_VP);
#pragma unroll
        for (int g = 0; g < 4; ++g)
#pragma unroll
          for (int ki = 0; ki < 4; ++ki) {
            int d2 = dgt * 32 + 8 * g + 4 * h5 + ki - 128;
            float yv = fmaf(acc[dt][nt][4 * g + ki], sa[4 * g + ki], sb[4 * g + ki]);
            vp[(size_t)d2 * 4032 + ridx] = (unsigned short)f2bf(yv);
          }
      }
    }
  }
}

// ---------------- stage 2: Lc partials via MFMA, exp(k) inline ----------------
__launch_bounds__(256)
__global__ void lc_mfma(float* __restrict__ Y, float* __restrict__ ws) {
  __shared__ float R[4096];
  __shared__ float Rs[64];
  int bx = blockIdx.x, u = blockIdx.y, b = blockIdx.z;
  int tid = threadIdx.x;
  int lane = tid & 63, w = tid >> 6;
  int col = lane & 15, quad = lane >> 4;
  int slot = bx * 4 + w;
  const float* krow = Y + ((size_t)(b * 384 + 64 + u * 16 + col)) * NPIX;
  const uint32_t* vpb = (const uint32_t*)(Y + (size_t)b * BSTR + OFF_VP)
                        + (size_t)(u * 64 + col) * VPLANE;
  f32x4 acc[4];
#pragma unroll
  for (int vt = 0; vt < 4; ++vt) acc[vt] = (f32x4){0.f, 0.f, 0.f, 0.f};
  float ssum = 0.0f;
  for (int c = slot; c < 126; c += 64) {
    int p0 = c * 32 + quad * 8;
    int row = p0 / 72;
    int pc = p0 - row * 72;
    bool valid = (unsigned)(pc - 8) < 56u;   // pc in {8..56} -> real cols
    float4 k0, k1;
    if (valid) {
      const float* kp = krow + row * NW + pc - 8;
      k0 = *(const float4*)(kp);
      k1 = *(const float4*)(kp + 4);
    } else {
      k0.x = k0.y = k0.z = k0.w = -1e30f;
      k1 = k0;
    }
    float e0 = __expf(k0.x), e1 = __expf(k0.y), e2 = __expf(k0.z), e3 = __expf(k0.w);
    float e4 = __expf(k1.x), e5 = __expf(k1.y), e6 = __expf(k1.z), e7 = __expf(k1.w);
    ssum += (e0 + e1 + e2 + e3) + (e4 + e5 + e6 + e7);
    union { uint32_t d[4]; bf16x8 v; } kb;
    kb.d[0] = pk_trunc(e0, e1);
    kb.d[1] = pk_trunc(e2, e3);
    kb.d[2] = pk_trunc(e4, e5);
    kb.d[3] = pk_trunc(e6, e7);
    int vdw = c * 16 + quad * 4;
#pragma unroll
    for (int vt = 0; vt < 4; ++vt) {
      union { uint4 q; bf16x8 v; } vb;
      vb.q = *(const uint4*)(vpb + (size_t)(vt * 16) * VPLANE + vdw);
      acc[vt] = __builtin_amdgcn_mfma_f32_16x16x32_bf16(vb.v, kb.v, acc[vt], 0, 0, 0);
    }
  }
  ssum += __shfl_xor(ssum, 16);
  ssum += __shfl_xor(ssum, 32);
#pragma unroll
  for (int vt = 0; vt < 4; ++vt)
#pragma unroll
    for (int r = 0; r < 4; ++r)
      R[w * 1024 + vt * 256 + quad * 64 + r * 16 + col] = acc[vt][r];
  if (lane < 16) Rs[w * 16 + col] = ssum;
  __syncthreads();
  float* P = Y + (size_t)b * BSTR + OFF_PARTB + (size_t)(u * 16 + bx) * 1024;
  float4 s0 = *(const float4*)(R + tid * 4);
  float4 s1 = *(const float4*)(R + 1024 + tid * 4);
  float4 s2 = *(const float4*)(R + 2048 + tid * 4);
  float4 s3 = *(const float4*)(R + 3072 + tid * 4);
  float4 tot;
  tot.x = (s0.x + s1.x) + (s2.x + s3.x);
  tot.y = (s0.y + s1.y) + (s2.y + s3.y);
  tot.z = (s0.z + s1.z) + (s2.z + s3.z);
  tot.w = (s0.w + s1.w) + (s2.w + s3.w);
  *(float4*)(P + tid * 4) = tot;
  if (tid < 16)
    atomicAdd(&ws[OFF_KS + b * 64 + u * 16 + tid],
              (Rs[tid] + Rs[16 + tid]) + (Rs[32 + tid] + Rs[48 + tid]));
}

// ---------------- stage 3: reduce partials -> Lc (scaled by 1/S) --------------
__global__ void lc_reduce(const float* __restrict__ Y, float* __restrict__ ws) {
  int i = blockIdx.x, b = blockIdx.y;
  int t = threadIdx.x;
  __shared__ float invS[64];
  if (t < 64) invS[t] = 1.0f / ws[OFF_KS + b * 64 + t];
  __syncthreads();
  int idx = i * 256 + t;
  int k = idx & 15;
  const float* P = Y + (size_t)b * BSTR + OFF_PARTB;
  float tot = 0.0f;
#pragma unroll
  for (int u = 0; u < 4; ++u) {
    float su = 0.0f;
#pragma unroll
    for (int s = 0; s < 16; ++s) su += P[(size_t)(u * 16 + s) * 1024 + idx];
    tot += su * invS[u * 16 + k];
  }
  ws[OFF_LC + (b * 16 + k) * 64 + (idx >> 4)] = tot;
}

// ---------------- stage 4: MFMA position conv + fused output contraction ------
#define ROWS    29
#define RSTR2   72
#define UPITCH2 2088   // ROWS * RSTR2
#define LDSW2   8352   // 4 * UPITCH2

// Fully-unrolled conv core with compile-time phase window (halo skip).
template<int PPLO, int PPHI>
__device__ __forceinline__ void conv_accum(const uint32_t* __restrict__ S,
                                           const uint4* __restrict__ wt,
                                           int abase, int lane, f32x4* acc) {
#pragma unroll 1
  for (int u = 0; u < 4; ++u) {
    bf16x8 wf[8];
#pragma unroll
    for (int t = 0; t < 8; ++t) {
      union { uint4 q; bf16x8 v; } tmp;
      tmp.q = wt[(u * 8 + t) * 64 + lane];
      wf[t] = tmp.v;
    }
    int au = u * UPITCH2 + abase;
#pragma unroll
    for (int PP = PPLO; PP < PPHI; ++PP) {
      int a = au + PP * (2 * RSTR2);
      union { uint32_t u4[4]; bf16x8 v8; } bu;
      bu.u4[0] = S[a];     bu.u4[1] = S[a + 2];
      bu.u4[2] = S[a + 4]; bu.u4[3] = S[a + 6];
#pragma unroll
      for (int t = 0; t < 8; ++t) {
        int q = PP - t;
        if (q >= 0 && q < 7)
          acc[q] = __builtin_amdgcn_mfma_f32_16x16x32_bf16(wf[t], bu.v8, acc[q], 0, 0, 0);
      }
    }
  }
}

__launch_bounds__(512, 4)
__global__ void pos_lambda_mfma(const float* __restrict__ Y, const float* __restrict__ wsc,
                                const float* __restrict__ pos_b, float* __restrict__ out) {
  __shared__ __attribute__((aligned(16))) uint32_t S[LDSW2];
  int v = blockIdx.x, b = blockIdx.y, band = blockIdx.z;
  int rb = band * 14;
  int tid = threadIdx.x;
  // ---- stage padded v rows from pre-padded bf16 planes ----
  // entry i of a row holds bf16 pair (x[i-7], x[i-6]); built from padded row dwords
  // via v_alignbit. Tasks: 4u x 29rows x 9 groups-of-8-entries = 1044.
  const uint32_t* vpad = (const uint32_t*)(Y + (size_t)b * BSTR + OFF_VP);
  for (int ii = tid; ii < 1044; ii += 512) {
    int u = ii / 261;
    int rem = ii - u * 261;
    int row = rem / 9;
    int j3 = rem - row * 9;
    int gr = rb + row - 7;
    uint32_t d0 = 0, d1 = 0, d2 = 0, d3 = 0, d4 = 0;
    if ((unsigned)gr < (unsigned)NW) {
      const uint32_t* pr32 = vpad + (size_t)(u * 64 + v) * VPLANE + gr * VROWD + 4 * j3;
      d0 = pr32[0]; d1 = pr32[1]; d2 = pr32[2]; d3 = pr32[3]; d4 = pr32[4];
    }
    uint32_t* dst = S + u * UPITCH2 + row * RSTR2 + 8 * j3;
    uint4 w0, w1;
    w0.x = __builtin_amdgcn_alignbit(d1, d0, 16);  w0.y = d1;
    w0.z = __builtin_amdgcn_alignbit(d2, d1, 16);  w0.w = d2;
    w1.x = __builtin_amdgcn_alignbit(d3, d2, 16);  w1.y = d3;
    w1.z = __builtin_amdgcn_alignbit(d4, d3, 16);  w1.w = d4;
    *(uint4*)(dst)     = w0;
    *(uint4*)(dst + 4) = w1;
  }
  __syncthreads();
  int lane = tid & 63, wid = tid >> 6;
  int quad = lane >> 4, n = lane & 15;
  int dhp = quad >> 1;
  int ct = wid & 3, p = wid >> 2;
  int cb = (ct == 3) ? 40 : ct * 16;
  int sb = cb + n + (quad & 1) * 8;
  int abase = (p + dhp) * RSTR2 + sb;
  const uint4* wt = (const uint4*)(wsc + OFF_WT);
  // Lc + pos_b folded into the MFMA C-initializer
  float lcq[4];
#pragma unroll
  for (int r = 0; r < 4; ++r) {
    int k = quad * 4 + r;
    lcq[r] = wsc[OFF_LC + (b * 16 + k) * 64 + v] + pos_b[k];
  }
  f32x4 acc[7];
#pragma unroll
  for (int q = 0; q < 7; ++q) {
    acc[q][0] = lcq[0]; acc[q][1] = lcq[1]; acc[q][2] = lcq[2]; acc[q][3] = lcq[3];
  }
  // halo skip: band0 stages zero rows 0..6 -> phases 0..2 all-zero; band3 stages
  // zero rows 21..28 -> phases 11..13 all-zero. Compile-time windows.
  if (band == 0)      conv_accum<3, 14>(S, wt, abase, lane, acc);
  else if (band == 3) conv_accum<0, 11>(S, wt, abase, lane, acc);
  else                conv_accum<0, 14>(S, wt, abase, lane, acc);

  const uint2* qb2 = (const uint2*)(Y + (size_t)b * BSTR);
#pragma unroll
  for (int q = 0; q < 7; ++q) {
    int rr = rb + p + 2 * q;
    int pix = rr * NW + cb + n;
    float m0 = acc[q][0], m1 = acc[q][1];
    float m2 = acc[q][2], m3 = acc[q][3];
    float pp[4];
#pragma unroll
    for (int j = 0; j < 4; ++j) {
      int h = quad ^ j;
      uint2 qd = qb2[(h * 4 + quad) * NPIX + pix];
      float q0 = __uint_as_float(qd.x << 16);
      float q1 = __uint_as_float(qd.x & 0xffff0000u);
      float q2 = __uint_as_float(qd.y << 16);
      float q3 = __uint_as_float(qd.y & 0xffff0000u);
      pp[j] = fmaf(q0, m0, fmaf(q1, m1, fmaf(q2, m2, q3 * m3)));
    }
    float t0 = pp[0] + __shfl_xor(pp[1], 16);
    float t2 = pp[2] + __shfl_xor(pp[3], 16);
    float y  = t0 + __shfl_xor(t2, 32);
    out[((size_t)(b * 256 + quad * 64 + v)) * NPIX + pix] = y;
  }
}

extern "C" void kernel_launch(void* const* d_in, const int* in_sizes, int n_in,
                              void* d_out, int out_size, void* d_ws, size_t ws_size,
                              hipStream_t stream) {
  const float* x     = (const float*)d_in[0];
  const float* Wq    = (const float*)d_in[1];
  const float* Wk    = (const float*)d_in[2];
  const float* Wv    = (const float*)d_in[3];
  const float* pos_w = (const float*)d_in[4];
  const float* pos_b = (const float*)d_in[5];
  const float* gq    = (const float*)d_in[6];
  const float* bq    = (const float*)d_in[7];
  const float* mq    = (const float*)d_in[8];
  const float* vq    = (const float*)d_in[9];
  const float* gv    = (const float*)d_in[10];
  const float* bv    = (const float*)d_in[11];
  const float* mv    = (const float*)d_in[12];
  const float* vv    = (const float*)d_in[13];
  float* ws  = (float*)d_ws;
  float* out = (float*)d_out;
  float* Y   = ws + OFF_Y;

  prep_kernel<<<dim3(384), 256, 0, stream>>>(Wq, Wk, Wv, pos_w, gq, bq, mq, vq,
                                             gv, bv, mv, vv, ws);
  qkv_mfma<<<dim3(49, 16), 256, 0, stream>>>(x, ws, Y);
  lc_mfma<<<dim3(16, 4, 16), 256, 0, stream>>>(Y, ws);
  lc_reduce<<<dim3(4, 16), 256, 0, stream>>>(Y, ws);
  pos_lambda_mfma<<<dim3(64, 16, 4), 512, 0, stream>>>(Y, ws, pos_b, out);
}